// Round 14
// baseline (226.245 us; speedup 1.0000x reference)
//
#include <hip/hip_runtime.h>
#include <math.h>

// Problem constants (match reference)
#define B_SZ 2
#define P_SZ 8192
#define K_NB 48
#define NRAD 8
#define NJ 2048          // 32 basis * 64 c_in
#define PTS 8            // points per block
#define GSTRIDE 2052     // G row stride (16B-aligned)
#define EPS_D 1e-8f

// ---- fused transpose: features [B][64][P] -> featT [B][P][64]  (blocks 0..255)
//      W [32][64 c][64 j] -> Wt [nj=n*64+j][64 c]                (blocks 256..287)
__global__ __launch_bounds__(256) void k_transpose(const float* __restrict__ f,
                                                   const float* __restrict__ w,
                                                   float* __restrict__ ft,
                                                   float* __restrict__ wt) {
    __shared__ float tile[64][65];
    int blk = blockIdx.x;
    int t = threadIdx.x;
    if (blk < 256) {
        int b = blk >> 7;                  // P/64 = 128
        int p0 = (blk & 127) << 6;
        {
            int pp = t & 63, cq = t >> 6;  // cq 0..3
#pragma unroll
            for (int i = 0; i < 16; ++i) {
                int c = cq * 16 + i;
                tile[c][pp] = f[((size_t)b * 64 + c) * P_SZ + p0 + pp];  // coalesced over p
            }
        }
        __syncthreads();
        {
            int cc = t & 63, pq = t >> 6;
#pragma unroll
            for (int i = 0; i < 16; ++i) {
                int p = pq * 16 + i;
                ft[((size_t)b * P_SZ + p0 + p) * 64 + cc] = tile[cc][p];  // coalesced over c
            }
        }
    } else {
        int n = blk - 256;  // 0..31
        {
            int jj = t & 63, cq = t >> 6;
#pragma unroll
            for (int i = 0; i < 16; ++i) {
                int c = cq * 16 + i;
                tile[c][jj] = w[((size_t)n * 64 + c) * 64 + jj];  // coalesced over j
            }
        }
        __syncthreads();
        {
            int cc = t & 63, jq = t >> 6;
#pragma unroll
            for (int i = 0; i < 16; ++i) {
                int j = jq * 16 + i;
                wt[((size_t)n * 64 + j) * 64 + cc] = tile[cc][j];  // coalesced over c
            }
        }
    }
}

// ---------------- main fused kernel ------------------------------------------
// block = 1024 threads = 16 waves, PTS = 8 points.
//
// R13 post-mortem: DMA staging of phase A was NEUTRAL (170us, VALUBusy 52%
// unchanged) -> gather latency was not the stall; the kernel is TLP-bound at
// 2 waves/SIMD (one 512-thread block/CU; measured R1/R5/R7/R13). Fix: 16-wave
// block -> 4 waves/SIMD from a SINGLE resident block, sidestepping the
// blocks/CU limit. Per-thread work halves:
//   phase A: 2 waves/point split by j-half (no write conflicts), 16 FMA/edge
//   phase B: 4 c's/thread (acc2[4][8]), 2-stage butterfly + 16-wave LDS reduce
// LDS: G 65.7K + sh 6.1K + d 1.5K + nbrs 1.5K = 74.8KB (fstage dropped).
__global__ __launch_bounds__(1024) void k_main(const float* __restrict__ featT,
                                               const float* __restrict__ geometry,
                                               const int* __restrict__ neighbors,
                                               const float* __restrict__ rel_mask,
                                               const float* __restrict__ Wt,
                                               float* __restrict__ out) {
    __shared__ float G[PTS][GSTRIDE];
    __shared__ float sh_l[PTS][K_NB][4];
    __shared__ float d_l[PTS][K_NB];
    __shared__ int   nbrs_l[PTS][K_NB];

    const int t = threadIdx.x;
    const int blk = blockIdx.x;
    const int b = blk >> 10;                 // P/PTS = 1024 blocks per batch
    const int pt0 = (blk & 1023) * PTS;

    // ---- edge prep: distance + masked SH + neighbor idx ---------------------
    if (t < PTS * K_NB) {
        int pt = t / K_NB;
        int k = t - pt * K_NB;
        int p = pt0 + pt;
        size_t base = (size_t)b * P_SZ + p;
        int nb = neighbors[base * K_NB + k];
        const float* gp = &geometry[base * 3];
        const float* gn = &geometry[((size_t)b * P_SZ + nb) * 3];
        float rx = gn[0] - gp[0], ry = gn[1] - gp[1], rz = gn[2] - gp[2];
        float d = sqrtf(rx * rx + ry * ry + rz * rz);
        float mask = rel_mask[base * K_NB + k];
        float inv = (d > EPS_D) ? (1.0f / d) : 0.0f;   // matches jnp.where semantics
        sh_l[pt][k][0] = mask;
        sh_l[pt][k][1] = rx * inv * mask;
        sh_l[pt][k][2] = ry * inv * mask;
        sh_l[pt][k][3] = rz * inv * mask;
        d_l[pt][k] = d;
        nbrs_l[pt][k] = nb;
    }
    __syncthreads();

    // ---- phase A: G[pt][n*64+j] = sum_k basis[k][n] * feat[nbr_k][j] --------
    // wave w (0..15): point pt = w>>1, j-half h = w&1 (channels h*32..h*32+31).
    // thread: ng = lane>>3 (radial), jg = lane&7 -> 4 channels, acc[4][4].
    {
        const int wave = t >> 6;
        const int lane = t & 63;
        const int pt = wave >> 1;
        const int h  = wave & 1;
        const int ng = lane >> 3;
        const int jg = lane & 7;
        const int j0 = h * 32 + jg * 4;
        const float center = (float)ng * (2.0f / 7.0f);  // linspace(0,2,8)[ng]
        float acc[4][4];
#pragma unroll
        for (int s = 0; s < 4; ++s)
#pragma unroll
            for (int j = 0; j < 4; ++j) acc[s][j] = 0.0f;

        const float* fbase = featT + (size_t)b * P_SZ * 64;
#pragma unroll 4
        for (int k = 0; k < K_NB; ++k) {
            int nb = nbrs_l[pt][k];
            float4 fv = *(const float4*)(fbase + (size_t)nb * 64 + j0);
            float z = (d_l[pt][k] - center) * 4.0f;      // 1/SIGMA = 4
            float rad = __expf(-0.5f * z * z);
            float4 s4 = *(const float4*)&sh_l[pt][k][0];
            float bs[4] = {rad * s4.x, rad * s4.y, rad * s4.z, rad * s4.w};
            float fj[4] = {fv.x, fv.y, fv.z, fv.w};
#pragma unroll
            for (int s = 0; s < 4; ++s)
#pragma unroll
                for (int j = 0; j < 4; ++j) acc[s][j] += bs[s] * fj[j];
        }
        const int n0 = ng * 4;
#pragma unroll
        for (int s = 0; s < 4; ++s)
            *(float4*)&G[pt][(n0 + s) * 64 + j0] = make_float4(acc[s][0], acc[s][1], acc[s][2], acc[s][3]);
    }
    __syncthreads();

    // ---- phase B: out[c][pt] = sum_nj Wt[nj][c] * G[pt][nj] -----------------
    // thread: cg = t&15 (4 c's), sg = t>>4 (64 slices of 32 nj). Rotation of
    // nj within the slice spreads the 4 in-wave slice groups across banks.
    float acc2[4][8];   // [ci][pt]
    {
        const int cg = t & 15;
        const int sg = t >> 4;
        const int c0 = cg * 4;
#pragma unroll
        for (int ci = 0; ci < 4; ++ci)
#pragma unroll
            for (int pt = 0; pt < 8; ++pt) acc2[ci][pt] = 0.0f;

        const int njbase = sg * 32;
        const int rot = (sg * 4) & 31;
#pragma unroll
        for (int it = 0; it < 8; ++it) {
            const int njo = njbase + ((it * 4 + rot) & 31);
            float4 g4[8];
#pragma unroll
            for (int pt = 0; pt < 8; ++pt) g4[pt] = *(const float4*)&G[pt][njo];
            float gf[8][4];
#pragma unroll
            for (int pt = 0; pt < 8; ++pt) {
                gf[pt][0] = g4[pt].x; gf[pt][1] = g4[pt].y;
                gf[pt][2] = g4[pt].z; gf[pt][3] = g4[pt].w;
            }
            float wf[4][4];
#pragma unroll
            for (int q = 0; q < 4; ++q) {
                float4 w0 = *(const float4*)(Wt + (size_t)(njo + q) * 64 + c0);
                wf[q][0] = w0.x; wf[q][1] = w0.y; wf[q][2] = w0.z; wf[q][3] = w0.w;
            }
#pragma unroll
            for (int q = 0; q < 4; ++q)
#pragma unroll
                for (int ci = 0; ci < 4; ++ci)
#pragma unroll
                    for (int pt = 0; pt < 8; ++pt)
                        acc2[ci][pt] += wf[q][ci] * gf[pt][q];
        }

        // in-wave butterfly over the 2 slice bits (lanes 16, 32 apart)
#pragma unroll
        for (int off = 16; off <= 32; off <<= 1)
#pragma unroll
            for (int ci = 0; ci < 4; ++ci)
#pragma unroll
                for (int pt = 0; pt < 8; ++pt)
                    acc2[ci][pt] += __shfl_xor(acc2[ci][pt], off, 64);
    }
    __syncthreads();   // all G reads done -> safe to overlay partials on G

    // cross-wave reduction: 16 wave-partials per output, staged in dead G space
    // layout: partial[w][c][pt] stride 9 over pt -> w*576 + c*9 + pt (36.9KB < G)
    float* partial = &G[0][0];
    {
        const int lane = t & 63;
        if (lane < 16) {                 // these lanes hold the wave-summed acc2
            const int w = t >> 6;
            const int cg = lane;
#pragma unroll
            for (int ci = 0; ci < 4; ++ci) {
                int c = cg * 4 + ci;
#pragma unroll
                for (int pt = 0; pt < 8; ++pt)
                    partial[w * 576 + c * 9 + pt] = acc2[ci][pt];
            }
        }
    }
    __syncthreads();
    if (t < 512) {
        const int c = t >> 3, pt = t & 7;
        float s = 0.0f;
#pragma unroll
        for (int w = 0; w < 16; ++w) s += partial[w * 576 + c * 9 + pt];
        out[((size_t)b * 64 + c) * P_SZ + pt0 + pt] = s;
    }
}

extern "C" void kernel_launch(void* const* d_in, const int* in_sizes, int n_in,
                              void* d_out, int out_size, void* d_ws, size_t ws_size,
                              hipStream_t stream) {
    const float* features  = (const float*)d_in[0];
    const float* geometry  = (const float*)d_in[1];
    const int*   neighbors = (const int*)d_in[2];
    const float* rel_mask  = (const float*)d_in[3];
    const float* W         = (const float*)d_in[4];
    float* out = (float*)d_out;

    float* featT = (float*)d_ws;                                   // 4 MB
    float* Wt    = (float*)((char*)d_ws + (size_t)B_SZ * P_SZ * 64 * 4);  // 512 KB

    k_transpose<<<288, 256, 0, stream>>>(features, W, featT, Wt);
    k_main<<<B_SZ * (P_SZ / PTS), 1024, 0, stream>>>(featT, geometry, neighbors,
                                                     rel_mask, Wt, out);
}